// Round 12
// baseline (175.175 us; speedup 1.0000x reference)
//
#include <hip/hip_runtime.h>

#define IN_F    4096
#define OUT_F   4096
#define K_DIM   4096
#define NNZ_C   838860
#define NQ      (NNZ_C / 4)              // 209715 entry-quads, exact
#define BATCH   512
#define BK      32
#define BM      128
#define BN      128

typedef short bf16x8 __attribute__((ext_vector_type(8)));
typedef float f32x4  __attribute__((ext_vector_type(4)));
typedef unsigned int u32x4 __attribute__((ext_vector_type(4)));   // nt-store-able

__device__ __forceinline__ unsigned short f2bf(float f) {  // RNE fp32->bf16
    unsigned u = __float_as_uint(f);
    u += 0x7fffu + ((u >> 16) & 1u);
    return (unsigned short)(u >> 16);
}
__device__ __forceinline__ void gload_lds16(const void* g, void* l) {
    __builtin_amdgcn_global_load_lds(
        (const __attribute__((address_space(1))) unsigned int*)g,
        (__attribute__((address_space(3))) unsigned int*)l, 16, 0, 0);
}
__device__ __forceinline__ void pk_add(unsigned short* W, unsigned idx, float v) {
    unsigned short h = f2bf(v);
    unsigned data = (idx & 1u) ? ((unsigned)h << 16) : (unsigned)h;
    unsigned long long addr = (unsigned long long)(W + (idx & ~1u));
    asm volatile("global_atomic_pk_add_bf16 %0, %1, off"
                 :: "v"(addr), "v"(data) : "memory");
}

// ---------------------------------------------------------------------------
// K1 "prep": (a) zero W with NON-TEMPORAL stores, (b) x fp32->bf16,
// (c) optional out=bias (fallback path only).
// R11 theory: normal zero-stores leave W's 524K lines dirty in per-XCD L2s;
// the scatter's device-scope atomics (executed at the coherence point) then
// pull each dirty line cross-die -- that fabric round-trip, not atomic ALU
// rate, is scatter's 44 us. nt stores stream the zeros past L2 so the
// atomics find lines already at the LLC.
// ---------------------------------------------------------------------------
#define N_WZ   (OUT_F * K_DIM / 8)       // u32x4 stores
#define N_CVT  (BATCH * K_DIM / 8)       // bf16x8 outputs
#define N_OUT  (BATCH * OUT_F / 4)       // float4 stores
__global__ void prep(const float* __restrict__ x,
                     unsigned short* __restrict__ xb,
                     const float* __restrict__ bias,
                     float* __restrict__ out,
                     u32x4* __restrict__ Wz, int do_bias) {
    int i = blockIdx.x * 256 + threadIdx.x;
    if (i < N_WZ) {
        __builtin_nontemporal_store((u32x4){0u, 0u, 0u, 0u}, &Wz[i]);
        return;
    }
    i -= N_WZ;
    if (i < N_CVT) {
        const float4* p = (const float4*)x + (size_t)i * 2;
        float4 a = p[0], b = p[1];
        union { unsigned short h[8]; bf16x8 v; } u;
        u.h[0] = f2bf(a.x); u.h[1] = f2bf(a.y); u.h[2] = f2bf(a.z); u.h[3] = f2bf(a.w);
        u.h[4] = f2bf(b.x); u.h[5] = f2bf(b.y); u.h[6] = f2bf(b.z); u.h[7] = f2bf(b.w);
        ((bf16x8*)xb)[i] = u.v;
        return;
    }
    i -= N_CVT;
    if (i < N_OUT && do_bias) {
        float4 b = ((const float4*)bias)[i & (OUT_F / 4 - 1)];
        ((float4*)out)[i] = b;
    }
}
#define PREP_BLOCKS ((N_WZ + N_CVT + N_OUT) / 256)

// ---------------------------------------------------------------------------
// K2: COO scatter-add, 4 entries/thread, fire-and-forget packed-bf16 atomic
// fadd (exact duplicate handling, no returning atomics -- R4 lesson).
// ---------------------------------------------------------------------------
__global__ void scatter_pk(const int* __restrict__ row_idx,
                           const int* __restrict__ col_idx,
                           const float* __restrict__ values,
                           unsigned short* __restrict__ W) {
    int i = blockIdx.x * 256 + threadIdx.x;
    if (i >= NQ) return;
    int4   r4 = ((const int4*)row_idx)[i];
    int4   c4 = ((const int4*)col_idx)[i];
    float4 v4 = ((const float4*)values)[i];
    pk_add(W, (unsigned)r4.x * K_DIM + (unsigned)c4.x, v4.x);
    pk_add(W, (unsigned)r4.y * K_DIM + (unsigned)c4.y, v4.y);
    pk_add(W, (unsigned)r4.z * K_DIM + (unsigned)c4.z, v4.z);
    pk_add(W, (unsigned)r4.w * K_DIM + (unsigned)c4.w, v4.w);
}

// ---------------------------------------------------------------------------
// K3: bf16 GEMM, B^T layout, 128x128xBK32, XOR swizzle (R6: 0 bank
// conflicts). EPI 0 (SK=8): split0 -> out (+bias) normal stores; s>0 ->
// parts[s-1] NON-TEMPORAL stores (written once, read once by another XCD's
// reduce block -- don't dirty local L2 with 58.7 MB).
// EPI 1: atomicAdd into bias-initialized out (fallback).
// ---------------------------------------------------------------------------
template <int EPI, int SK>
__global__ void __launch_bounds__(256)
gemm_bt(const unsigned short* __restrict__ Abf,   // [512][4096] bf16
        const unsigned short* __restrict__ Wbf,   // [4096][4096] bf16
        const float* __restrict__ bias,
        float* __restrict__ out,                  // [512][4096] f32
        float* __restrict__ parts) {              // (SK-1) x [512][4096] f32
    __shared__ __align__(16) unsigned short As[BM * BK];   // 8 KB
    __shared__ __align__(16) unsigned short Bs[BN * BK];   // 8 KB

    const int nt = blockIdx.x, mt = blockIdx.y, s = blockIdx.z;
    const int t = threadIdx.x, w = t >> 6, ln = t & 63;
    const int wm = w & 1, wn = w >> 1;
    const int KSs = K_DIM / SK;
    const int ks0 = s * KSs;

    // staging: lane ln -> LDS row (ln>>2), physical chunk (ln&3);
    // global source = logical chunk (ln&3) ^ ((ln>>3)&3)   [R6: 0 conflicts]
    const int srow = w * 16 + (ln >> 2);
    const int scol = (((ln & 3) ^ ((ln >> 3) & 3)) * 8);
    const unsigned short* gA0 = Abf + (size_t)(mt * BM + srow) * K_DIM + ks0 + scol;
    const unsigned short* gA1 = gA0 + (size_t)64 * K_DIM;
    const unsigned short* gB0 = Wbf + (size_t)(nt * BN + srow) * K_DIM + ks0 + scol;
    const unsigned short* gB1 = gB0 + (size_t)64 * K_DIM;
    unsigned short* lA0 = &As[(w * 16) * BK];
    unsigned short* lA1 = &As[(64 + w * 16) * BK];
    unsigned short* lB0 = &Bs[(w * 16) * BK];
    unsigned short* lB1 = &Bs[(64 + w * 16) * BK];

    // read: logical quad q -> physical chunk q ^ ((lanem>>1)&3)
    const int quad = ln >> 4, lanem = ln & 15;
    const int rsw = (quad ^ ((lanem >> 1) & 3)) * 8;
    const unsigned short* rA = &As[(wm * 64 + lanem) * BK + rsw];
    const unsigned short* rB = &Bs[(wn * 64 + lanem) * BK + rsw];

    f32x4 acc[4][4];
#pragma unroll
    for (int mi = 0; mi < 4; ++mi)
#pragma unroll
        for (int ni = 0; ni < 4; ++ni)
            acc[mi][ni] = (f32x4){0.f, 0.f, 0.f, 0.f};

    for (int kt = 0; kt < KSs / BK; ++kt) {
        __syncthreads();
        gload_lds16(gA0 + kt * BK, lA0);
        gload_lds16(gA1 + kt * BK, lA1);
        gload_lds16(gB0 + kt * BK, lB0);
        gload_lds16(gB1 + kt * BK, lB1);
        __syncthreads();

        bf16x8 af[4], bfr[4];
#pragma unroll
        for (int mi = 0; mi < 4; ++mi) af[mi]  = *(const bf16x8*)(rA + mi * 16 * BK);
#pragma unroll
        for (int ni = 0; ni < 4; ++ni) bfr[ni] = *(const bf16x8*)(rB + ni * 16 * BK);
#pragma unroll
        for (int mi = 0; mi < 4; ++mi)
#pragma unroll
            for (int ni = 0; ni < 4; ++ni)
                acc[mi][ni] = __builtin_amdgcn_mfma_f32_16x16x32_bf16(
                    af[mi], bfr[ni], acc[mi][ni], 0, 0, 0);
    }

    // C/D layout: col = lanem, row = quad*4 + r; 16 lanes = one 64B segment.
    const int row0 = mt * BM + wm * 64 + quad * 4;
    const int col0 = nt * BN + wn * 64 + lanem;
    if (EPI == 0) {
        if (s == 0) {
            float bv[4];
#pragma unroll
            for (int ni = 0; ni < 4; ++ni) bv[ni] = bias[col0 + ni * 16];
#pragma unroll
            for (int mi = 0; mi < 4; ++mi)
#pragma unroll
                for (int ni = 0; ni < 4; ++ni)
#pragma unroll
                    for (int r = 0; r < 4; ++r)
                        out[(size_t)(row0 + mi * 16 + r) * OUT_F + col0 + ni * 16] =
                            acc[mi][ni][r] + bv[ni];
        } else {
            float* dst = parts + (size_t)(s - 1) * BATCH * OUT_F;
#pragma unroll
            for (int mi = 0; mi < 4; ++mi)
#pragma unroll
                for (int ni = 0; ni < 4; ++ni)
#pragma unroll
                    for (int r = 0; r < 4; ++r)
                        __builtin_nontemporal_store(
                            acc[mi][ni][r],
                            &dst[(size_t)(row0 + mi * 16 + r) * OUT_F + col0 + ni * 16]);
        }
    } else {
#pragma unroll
        for (int mi = 0; mi < 4; ++mi)
#pragma unroll
            for (int ni = 0; ni < 4; ++ni)
#pragma unroll
                for (int r = 0; r < 4; ++r)
                    atomicAdd(&out[(size_t)(row0 + mi * 16 + r) * OUT_F + col0 + ni * 16],
                              acc[mi][ni][r]);
    }
}

// ---------------------------------------------------------------------------
// K4: out += sum(parts[0..6])  (75 MB streamed)
// ---------------------------------------------------------------------------
__global__ void reduce_parts(float* __restrict__ out,
                             const float* __restrict__ parts) {
    int i = blockIdx.x * 256 + threadIdx.x;          // 524288 float4s
    float4 a = ((const float4*)out)[i];
#pragma unroll
    for (int p = 0; p < 7; ++p) {
        float4 b = ((const float4*)(parts + (size_t)p * BATCH * OUT_F))[i];
        a.x += b.x; a.y += b.y; a.z += b.z; a.w += b.w;
    }
    ((float4*)out)[i] = a;
}

// ---------------------------------------------------------------------------
// ws: xb 4.19 | W 33.55 | parts 7 x 8.39 = 58.72  -> 96.5 MB (fallback if less)
// ---------------------------------------------------------------------------
extern "C" void kernel_launch(void* const* d_in, const int* in_sizes, int n_in,
                              void* d_out, int out_size, void* d_ws, size_t ws_size,
                              hipStream_t stream) {
    const float* x       = (const float*)d_in[0];
    const int*   row_idx = (const int*)d_in[1];
    const int*   col_idx = (const int*)d_in[2];
    const float* values  = (const float*)d_in[3];
    const float* bias    = (const float*)d_in[4];
    float*       out     = (float*)d_out;

    unsigned short* xb = (unsigned short*)d_ws;
    unsigned short* W  = xb + (size_t)BATCH * K_DIM;
    float* parts = (float*)(W + (size_t)OUT_F * K_DIM);
    size_t need = (size_t)BATCH * K_DIM * 2 + (size_t)OUT_F * K_DIM * 2
                + (size_t)7 * BATCH * OUT_F * 4;
    bool use_parts = (ws_size >= need);

    prep<<<PREP_BLOCKS, 256, 0, stream>>>(x, xb, bias, out, (u32x4*)W,
                                          use_parts ? 0 : 1);
    scatter_pk<<<(NQ + 255) / 256, 256, 0, stream>>>(
        row_idx, col_idx, values, W);

    if (use_parts) {
        gemm_bt<0, 8><<<dim3(OUT_F / BN, BATCH / BM, 8), 256, 0, stream>>>(
            xb, W, bias, out, parts);
        reduce_parts<<<BATCH * OUT_F / 4 / 256, 256, 0, stream>>>(out, parts);
    } else {
        gemm_bt<1, 4><<<dim3(OUT_F / BN, BATCH / BM, 4), 256, 0, stream>>>(
            xb, W, bias, out, nullptr);
    }
}

// Round 13
// 164.815 us; speedup vs baseline: 1.0629x; 1.0629x over previous
//
#include <hip/hip_runtime.h>

#define IN_F    4096
#define OUT_F   4096
#define K_DIM   4096
#define NNZ_C   838860
#define NQ      (NNZ_C / 4)              // 209715 entry-quads, exact
#define BATCH   512
#define BK      32
#define BM      128
#define BN      128
#define NBLK    1024                     // 4 blocks/CU x 256 CUs
#define NCHUNK  8                        // = SK; chunk c = cols [c*512,(c+1)*512)

typedef short bf16x8 __attribute__((ext_vector_type(8)));
typedef float f32x4  __attribute__((ext_vector_type(4)));

__device__ __forceinline__ unsigned short f2bf(float f) {  // RNE fp32->bf16
    unsigned u = __float_as_uint(f);
    u += 0x7fffu + ((u >> 16) & 1u);
    return (unsigned short)(u >> 16);
}
__device__ __forceinline__ void gload_lds16(const void* g, void* l) {
    __builtin_amdgcn_global_load_lds(
        (const __attribute__((address_space(1))) unsigned int*)g,
        (__attribute__((address_space(3))) unsigned int*)l, 16, 0, 0);
}
__device__ __forceinline__ void pk_add(unsigned short* W, unsigned idx, float v) {
    unsigned short h = f2bf(v);
    unsigned data = (idx & 1u) ? ((unsigned)h << 16) : (unsigned)h;
    unsigned long long addr = (unsigned long long)(W + (idx & ~1u));
    asm volatile("global_atomic_pk_add_bf16 %0, %1, off"
                 :: "v"(addr), "v"(data) : "memory");
}

// ---------------------------------------------------------------------------
// R8's verified GEMM body: 128x128xBK32, XOR swizzle (0 bank conflicts).
// EPI 0: split0 -> out (+bias), s>0 -> parts[s-1], plain stores.
// EPI 1: atomicAdd into bias-initialized out (fallback).
// ---------------------------------------------------------------------------
template <int EPI, int SK>
__device__ __forceinline__ void gemm_body(
    int nt, int mt, int s, int t,
    const unsigned short* __restrict__ Abf,
    const unsigned short* __restrict__ Wbf,
    const float* __restrict__ bias,
    float* __restrict__ out, float* __restrict__ parts,
    unsigned short* As, unsigned short* Bs) {
    const int w = t >> 6, ln = t & 63;
    const int wm = w & 1, wn = w >> 1;
    const int KSs = K_DIM / SK;
    const int ks0 = s * KSs;

    const int srow = w * 16 + (ln >> 2);
    const int scol = (((ln & 3) ^ ((ln >> 3) & 3)) * 8);
    const unsigned short* gA0 = Abf + (size_t)(mt * BM + srow) * K_DIM + ks0 + scol;
    const unsigned short* gA1 = gA0 + (size_t)64 * K_DIM;
    const unsigned short* gB0 = Wbf + (size_t)(nt * BN + srow) * K_DIM + ks0 + scol;
    const unsigned short* gB1 = gB0 + (size_t)64 * K_DIM;
    unsigned short* lA0 = &As[(w * 16) * BK];
    unsigned short* lA1 = &As[(64 + w * 16) * BK];
    unsigned short* lB0 = &Bs[(w * 16) * BK];
    unsigned short* lB1 = &Bs[(64 + w * 16) * BK];

    const int quad = ln >> 4, lanem = ln & 15;
    const int rsw = (quad ^ ((lanem >> 1) & 3)) * 8;
    const unsigned short* rA = &As[(wm * 64 + lanem) * BK + rsw];
    const unsigned short* rB = &Bs[(wn * 64 + lanem) * BK + rsw];

    f32x4 acc[4][4];
#pragma unroll
    for (int mi = 0; mi < 4; ++mi)
#pragma unroll
        for (int ni = 0; ni < 4; ++ni)
            acc[mi][ni] = (f32x4){0.f, 0.f, 0.f, 0.f};

    for (int kt = 0; kt < KSs / BK; ++kt) {
        __syncthreads();
        gload_lds16(gA0 + kt * BK, lA0);
        gload_lds16(gA1 + kt * BK, lA1);
        gload_lds16(gB0 + kt * BK, lB0);
        gload_lds16(gB1 + kt * BK, lB1);
        __syncthreads();

        bf16x8 af[4], bfr[4];
#pragma unroll
        for (int mi = 0; mi < 4; ++mi) af[mi]  = *(const bf16x8*)(rA + mi * 16 * BK);
#pragma unroll
        for (int ni = 0; ni < 4; ++ni) bfr[ni] = *(const bf16x8*)(rB + ni * 16 * BK);
#pragma unroll
        for (int mi = 0; mi < 4; ++mi)
#pragma unroll
            for (int ni = 0; ni < 4; ++ni)
                acc[mi][ni] = __builtin_amdgcn_mfma_f32_16x16x32_bf16(
                    af[mi], bfr[ni], acc[mi][ni], 0, 0, 0);
    }

    const int row0 = mt * BM + wm * 64 + quad * 4;
    const int col0 = nt * BN + wn * 64 + lanem;
    if (EPI == 0) {
        if (s == 0) {
            float bv[4];
#pragma unroll
            for (int ni = 0; ni < 4; ++ni) bv[ni] = bias[col0 + ni * 16];
#pragma unroll
            for (int mi = 0; mi < 4; ++mi)
#pragma unroll
                for (int ni = 0; ni < 4; ++ni)
#pragma unroll
                    for (int r = 0; r < 4; ++r)
                        out[(size_t)(row0 + mi * 16 + r) * OUT_F + col0 + ni * 16] =
                            acc[mi][ni][r] + bv[ni];
        } else {
            float* dst = parts + (size_t)(s - 1) * BATCH * OUT_F;
#pragma unroll
            for (int mi = 0; mi < 4; ++mi)
#pragma unroll
                for (int ni = 0; ni < 4; ++ni)
#pragma unroll
                    for (int r = 0; r < 4; ++r)
                        dst[(size_t)(row0 + mi * 16 + r) * OUT_F + col0 + ni * 16] =
                            acc[mi][ni][r];
        }
    } else {
#pragma unroll
        for (int mi = 0; mi < 4; ++mi)
#pragma unroll
            for (int ni = 0; ni < 4; ++ni)
#pragma unroll
                for (int r = 0; r < 4; ++r)
                    atomicAdd(&out[(size_t)(row0 + mi * 16 + r) * OUT_F + col0 + ni * 16],
                              acc[mi][ni][r]);
    }
}

// ---------------------------------------------------------------------------
// K1: x fp32 -> bf16 (one bf16x8 per thread; 1024 blocks)
// ---------------------------------------------------------------------------
__global__ void cvt_x(const float* __restrict__ x,
                      unsigned short* __restrict__ xb) {
    int i = blockIdx.x * 256 + threadIdx.x;
    const float4* p = (const float4*)x + (size_t)i * 2;
    float4 a = p[0], b = p[1];
    union { unsigned short h[8]; bf16x8 v; } u;
    u.h[0] = f2bf(a.x); u.h[1] = f2bf(a.y); u.h[2] = f2bf(a.z); u.h[3] = f2bf(a.w);
    u.h[4] = f2bf(b.x); u.h[5] = f2bf(b.y); u.h[6] = f2bf(b.z); u.h[7] = f2bf(b.w);
    ((bf16x8*)xb)[i] = u.v;
}

// ---------------------------------------------------------------------------
// K2: FUSED scatter + gemm, producer-consumer by K-chunk.
// Every block: (1) loads its <=4 COO entries into registers; (2) for chunk
// c=0..7 issues the entries whose col-chunk == c (fire-and-forget pk_add),
// drains vmcnt, syncthreads, thread0 release-arrives on done[c]; (3) spins
// (acquire + s_sleep) until done[s]==1024 where s = its gemm split; (4) runs
// R8's gemm body. Chunk c = W cols [c*512,(c+1)*512) -- exactly what gemm
// split c reads; boundaries are 1024B = line-aligned (no straddle).
// Splits interleave across CUs (s = b>>7; CU-strided blocks differ in s), so
// early-chunk gemm work fills the CUs while late-chunk atomics drain.
// Occupancy-gated at launch (all 1024 blocks co-resident or fallback).
// ---------------------------------------------------------------------------
__global__ void __launch_bounds__(256, 4)
scatter_gemm(const int* __restrict__ row_idx,
             const int* __restrict__ col_idx,
             const float* __restrict__ values,
             const unsigned short* __restrict__ xb,
             unsigned short* __restrict__ W,
             const float* __restrict__ bias,
             float* __restrict__ out,
             float* __restrict__ parts,
             int* __restrict__ done) {      // 8 counters, 128B apart
    __shared__ __align__(16) unsigned short As[BM * BK];
    __shared__ __align__(16) unsigned short Bs[BN * BK];
    const int b = blockIdx.x, t = threadIdx.x;
    const int g = b * 256 + t;

    unsigned eidx[4];
    float    ev[4];
    const bool have = (g < NQ);
    if (have) {
        int4   r4 = ((const int4*)row_idx)[g];
        int4   c4 = ((const int4*)col_idx)[g];
        float4 v4 = ((const float4*)values)[g];
        eidx[0] = (unsigned)r4.x * K_DIM + (unsigned)c4.x;  ev[0] = v4.x;
        eidx[1] = (unsigned)r4.y * K_DIM + (unsigned)c4.y;  ev[1] = v4.y;
        eidx[2] = (unsigned)r4.z * K_DIM + (unsigned)c4.z;  ev[2] = v4.z;
        eidx[3] = (unsigned)r4.w * K_DIM + (unsigned)c4.w;  ev[3] = v4.w;
    }

    for (int c = 0; c < NCHUNK; ++c) {
        if (have) {
#pragma unroll
            for (int j = 0; j < 4; ++j)
                if ((int)((eidx[j] >> 9) & 7u) == c) pk_add(W, eidx[j], ev[j]);
        }
        asm volatile("s_waitcnt vmcnt(0)" ::: "memory");   // my atomics done
        __syncthreads();                                   // whole block done
        if (t == 0)
            __hip_atomic_fetch_add(&done[c * 32], 1,
                                   __ATOMIC_RELEASE, __HIP_MEMORY_SCOPE_AGENT);
    }

    const int s = b >> 7, nt = b & 31, mt = (b >> 5) & 3;
    if (t == 0) {
        while (__hip_atomic_load(&done[s * 32], __ATOMIC_ACQUIRE,
                                 __HIP_MEMORY_SCOPE_AGENT) < NBLK)
            __builtin_amdgcn_s_sleep(8);
    }
    __syncthreads();

    gemm_body<0, 8>(nt, mt, s, t, xb, W, bias, out, parts, As, Bs);
}

// ---------------------------------------------------------------------------
// K3: out += sum(parts[0..6])
// ---------------------------------------------------------------------------
__global__ void reduce_parts(float* __restrict__ out,
                             const float* __restrict__ parts) {
    int i = blockIdx.x * 256 + threadIdx.x;          // 524288 float4s
    float4 a = ((const float4*)out)[i];
#pragma unroll
    for (int p = 0; p < 7; ++p) {
        float4 b = ((const float4*)(parts + (size_t)p * BATCH * OUT_F))[i];
        a.x += b.x; a.y += b.y; a.z += b.z; a.w += b.w;
    }
    ((float4*)out)[i] = a;
}

// ---------------------------------------------------------------------------
// Fallback path (R8-proven, plain stores -- nt reverted per R12).
// ---------------------------------------------------------------------------
#define N_WZ   (OUT_F * K_DIM / 8)
#define N_CVT  (BATCH * K_DIM / 8)
#define N_OUT  (BATCH * OUT_F / 4)
__global__ void prep(const float* __restrict__ x,
                     unsigned short* __restrict__ xb,
                     const float* __restrict__ bias,
                     float* __restrict__ out,
                     uint4* __restrict__ Wz, int do_bias) {
    int i = blockIdx.x * 256 + threadIdx.x;
    if (i < N_WZ) { Wz[i] = make_uint4(0, 0, 0, 0); return; }
    i -= N_WZ;
    if (i < N_CVT) {
        const float4* p = (const float4*)x + (size_t)i * 2;
        float4 a = p[0], b = p[1];
        union { unsigned short h[8]; bf16x8 v; } u;
        u.h[0] = f2bf(a.x); u.h[1] = f2bf(a.y); u.h[2] = f2bf(a.z); u.h[3] = f2bf(a.w);
        u.h[4] = f2bf(b.x); u.h[5] = f2bf(b.y); u.h[6] = f2bf(b.z); u.h[7] = f2bf(b.w);
        ((bf16x8*)xb)[i] = u.v;
        return;
    }
    i -= N_CVT;
    if (i < N_OUT && do_bias) {
        float4 b = ((const float4*)bias)[i & (OUT_F / 4 - 1)];
        ((float4*)out)[i] = b;
    }
}
__global__ void scatter_pk(const int* __restrict__ row_idx,
                           const int* __restrict__ col_idx,
                           const float* __restrict__ values,
                           unsigned short* __restrict__ W) {
    int i = blockIdx.x * 256 + threadIdx.x;
    if (i >= NQ) return;
    int4   r4 = ((const int4*)row_idx)[i];
    int4   c4 = ((const int4*)col_idx)[i];
    float4 v4 = ((const float4*)values)[i];
    pk_add(W, (unsigned)r4.x * K_DIM + (unsigned)c4.x, v4.x);
    pk_add(W, (unsigned)r4.y * K_DIM + (unsigned)c4.y, v4.y);
    pk_add(W, (unsigned)r4.z * K_DIM + (unsigned)c4.z, v4.z);
    pk_add(W, (unsigned)r4.w * K_DIM + (unsigned)c4.w, v4.w);
}
__global__ void __launch_bounds__(256)
gemm_k(const unsigned short* __restrict__ Abf,
       const unsigned short* __restrict__ Wbf,
       const float* __restrict__ bias,
       float* __restrict__ out, float* __restrict__ parts, int epi) {
    __shared__ __align__(16) unsigned short As[BM * BK];
    __shared__ __align__(16) unsigned short Bs[BN * BK];
    if (epi == 0)
        gemm_body<0, 8>(blockIdx.x, blockIdx.y, blockIdx.z, threadIdx.x,
                        Abf, Wbf, bias, out, parts, As, Bs);
    else
        gemm_body<1, 4>(blockIdx.x, blockIdx.y, blockIdx.z, threadIdx.x,
                        Abf, Wbf, bias, out, parts, As, Bs);
}

// ---------------------------------------------------------------------------
// ws: xb 4.19 MB | W 33.55 MB | done 4 KB | parts 58.72 MB  (~96.5 MB)
// One memset covers W+done (contiguous).
// ---------------------------------------------------------------------------
extern "C" void kernel_launch(void* const* d_in, const int* in_sizes, int n_in,
                              void* d_out, int out_size, void* d_ws, size_t ws_size,
                              hipStream_t stream) {
    const float* x       = (const float*)d_in[0];
    const int*   row_idx = (const int*)d_in[1];
    const int*   col_idx = (const int*)d_in[2];
    const float* values  = (const float*)d_in[3];
    const float* bias    = (const float*)d_in[4];
    float*       out     = (float*)d_out;

    char* p = (char*)d_ws;
    unsigned short* xb = (unsigned short*)p; p += (size_t)BATCH * K_DIM * 2;
    unsigned short* W  = (unsigned short*)p; p += (size_t)OUT_F * K_DIM * 2;
    int* done = (int*)p;                     p += 4096;
    float* parts = (float*)p;                p += (size_t)7 * BATCH * OUT_F * 4;
    size_t need_full = (size_t)(p - (char*)d_ws);
    size_t need_parts = need_full;           // same layout

    int maxb = 0;
    hipError_t e = hipOccupancyMaxActiveBlocksPerMultiprocessor(
        &maxb, (const void*)scatter_gemm, 256, 0);
    bool fuse = (e == hipSuccess) && (maxb >= 4) && (ws_size >= need_full);

    if (fuse) {
        hipMemsetAsync(W, 0, (size_t)OUT_F * K_DIM * 2 + 4096, stream);
        cvt_x<<<NBLK, 256, 0, stream>>>(x, xb);
        scatter_gemm<<<NBLK, 256, 0, stream>>>(row_idx, col_idx, values,
                                               xb, W, bias, out, parts, done);
        reduce_parts<<<BATCH * OUT_F / 4 / 256, 256, 0, stream>>>(out, parts);
    } else if (ws_size >= need_parts) {
        prep<<<(N_WZ + N_CVT + N_OUT) / 256, 256, 0, stream>>>(
            x, xb, bias, out, (uint4*)W, 0);
        scatter_pk<<<(NQ + 255) / 256, 256, 0, stream>>>(
            row_idx, col_idx, values, W);
        gemm_k<<<dim3(OUT_F / BN, BATCH / BM, 8), 256, 0, stream>>>(
            xb, W, bias, out, parts, 0);
        reduce_parts<<<BATCH * OUT_F / 4 / 256, 256, 0, stream>>>(out, parts);
    } else {
        prep<<<(N_WZ + N_CVT + N_OUT) / 256, 256, 0, stream>>>(
            x, xb, bias, out, (uint4*)W, 1);
        scatter_pk<<<(NQ + 255) / 256, 256, 0, stream>>>(
            row_idx, col_idx, values, W);
        gemm_k<<<dim3(OUT_F / BN, BATCH / BM, 4), 256, 0, stream>>>(
            xb, W, bias, out, nullptr, 1);
    }
}